// Round 2
// baseline (511.268 us; speedup 1.0000x reference)
//
#include <hip/hip_runtime.h>
#include <math.h>

// Problem shape (fixed by reference setup_inputs):
//   predictions, ground_truths: [BS=16, SEQ=4096, SRC=4, DIM=257] float32
//   out = sum over (b,src) of sqrt( sum over (seq,dim) diff^2 )
#define BS   16
#define SEQ  4096
#define SRC  4
#define DIM  257
#define NBUCKET (BS * SRC)              // 64
#define CHUNKS 64                       // blocks per bucket along seq
#define ROWS_PER_BLOCK (SEQ / CHUNKS)   // 64 seq rows per block
#define ROW_STRIDE (SRC * DIM)          // 1028 elements between same-bucket rows

// Compile-time specialized per-src row accumulator.
// Row base element offset ≡ src (mod 4), so k0 = (4-src)&3 prologue scalars
// reach 16B alignment; n4 float4 lanes cover the bulk; nscal edge scalars.
//   src=0: k0=0 n4=64 nscal=1   (dense float4, lane0 tail)
//   src=1: k0=3 n4=63 nscal=5
//   src=2: k0=2 n4=63 nscal=5
//   src=3: k0=1 n4=64 nscal=1   (dense float4, lane0 prologue)
template <int S>
__device__ __forceinline__ float rows_accum(const float* __restrict__ pred,
                                            const float* __restrict__ gt,
                                            long long base0, int lane, int wave)
{
    constexpr int k0    = (4 - S) & 3;
    constexpr int n4    = (DIM - k0) >> 2;
    constexpr int nscal = DIM - 4 * n4;

    float acc = 0.0f;

    #pragma unroll 4
    for (int r = wave; r < ROWS_PER_BLOCK; r += 4) {
        const long long base = base0 + (long long)r * ROW_STRIDE;

        if (n4 == 64 || lane < n4) {
            const float4 p = *(const float4*)(pred + base + k0 + 4 * lane);
            const float4 g = *(const float4*)(gt   + base + k0 + 4 * lane);
            const float dx = p.x - g.x;
            const float dy = p.y - g.y;
            const float dz = p.z - g.z;
            const float dw = p.w - g.w;
            acc += dx * dx + dy * dy + dz * dz + dw * dw;
        }
        if (lane < nscal) {
            const int off = (k0 > 0 && lane < k0) ? lane : (4 * n4 + lane);
            const float d = pred[base + off] - gt[base + off];
            acc += d * d;
        }
    }
    return acc;
}

// One block per (bucket, seq-chunk); bucket is block-uniform. Each block
// writes its partial sum to a distinct ws slot — no init, no atomics.
__global__ __launch_bounds__(256) void bucket_sq_sums(
    const float* __restrict__ pred,
    const float* __restrict__ gt,
    float* __restrict__ partial)        // [NBUCKET][CHUNKS]
{
    const int bucket = blockIdx.x;      // 0..63
    const int chunk  = blockIdx.y;      // 0..CHUNKS-1
    const int b      = bucket >> 2;
    const int src    = bucket & 3;
    const int wave   = threadIdx.x >> 6;
    const int lane   = threadIdx.x & 63;

    const long long base0 =
        (long long)b * (SEQ * ROW_STRIDE) +
        (long long)(chunk * ROWS_PER_BLOCK) * ROW_STRIDE +
        (long long)src * DIM;

    float acc;
    switch (src) {                      // block-uniform branch
        case 0:  acc = rows_accum<0>(pred, gt, base0, lane, wave); break;
        case 1:  acc = rows_accum<1>(pred, gt, base0, lane, wave); break;
        case 2:  acc = rows_accum<2>(pred, gt, base0, lane, wave); break;
        default: acc = rows_accum<3>(pred, gt, base0, lane, wave); break;
    }

    #pragma unroll
    for (int o = 32; o > 0; o >>= 1) acc += __shfl_down(acc, o, 64);

    __shared__ float s4[4];
    if (lane == 0) s4[wave] = acc;
    __syncthreads();
    if (threadIdx.x == 0)
        partial[bucket * CHUNKS + chunk] = s4[0] + s4[1] + s4[2] + s4[3];
}

// Single wave: lane t owns bucket t — sum its CHUNKS partials (contiguous
// 256 B per lane), sqrt, shuffle-reduce, write the scalar.
__global__ void finalize_kernel(const float* __restrict__ partial,
                                float* __restrict__ out)
{
    const int t = threadIdx.x;          // 0..63 == NBUCKET
    float s = 0.0f;
    #pragma unroll 8
    for (int c = 0; c < CHUNKS; ++c) s += partial[t * CHUNKS + c];
    float v = sqrtf(s);
    #pragma unroll
    for (int o = 32; o > 0; o >>= 1) v += __shfl_down(v, o, 64);
    if (t == 0) out[0] = v;
}

extern "C" void kernel_launch(void* const* d_in, const int* in_sizes, int n_in,
                              void* d_out, int out_size, void* d_ws, size_t ws_size,
                              hipStream_t stream)
{
    const float* pred = (const float*)d_in[0];
    const float* gt   = (const float*)d_in[1];
    float* partial = (float*)d_ws;      // 64*64 floats = 16 KB, fully overwritten
    float* out     = (float*)d_out;

    bucket_sq_sums<<<dim3(NBUCKET, CHUNKS), 256, 0, stream>>>(pred, gt, partial);
    finalize_kernel<<<1, 64, 0, stream>>>(partial, out);
}